// Round 10
// baseline (246.190 us; speedup 1.0000x reference)
//
#include <hip/hip_runtime.h>

constexpr int BATCH = 32;
constexpr int HH = 256, WW = 256;
constexpr int NPIX = HH * WW;
constexpr int STEPS = 15;
constexpr float R_C = 3.9f, EPS_C = 0.3f, BETA_C = 0.15f;
constexpr float CLAMP_LO = 1e-4f, CLAMP_HI = 1.0f - 1e-4f;

typedef __attribute__((ext_vector_type(8))) short short8;
typedef __attribute__((ext_vector_type(4))) float f32x4;

__device__ inline unsigned short f2bf(float f) {
  unsigned int u = __float_as_uint(f);
  return (unsigned short)((u + 0x7fffu + ((u >> 16) & 1u)) >> 16);
}

// packed f32x2 -> bf16x2 (RNE, bit-identical to f2bf pair); gfx950 VALU op
__device__ inline unsigned cvtpk(float lo, float hi) {
  unsigned r;
  asm("v_cvt_pk_bf16_f32 %0, %1, %2" : "=v"(r) : "v"(lo), "v"(hi));
  return r;
}

__constant__ int VT_OY[20] = {1,2,3,1, 3,0,0,2, 0,2,2,4, 4,4,3,2, 0,0,2,1};
__constant__ int VT_OX[20] = {3,2,3,1, 1,4,2,4, 0,2,0,2, 4,0,2,1, 1,3,3,2};
__constant__ int VT_SRC[20]= {0,0,0,0, 0,1,1,1, 1,1,1,1, 1,1,0,0, 2,2,0,0};
__constant__ int VT_TAP[20]= {2,4,8,0, 6,2,1,5, 0,4,3,7, 8,6,7,3, 0,0,5,1};

// ------------------------------------------------------------------ prep
__global__ void prep_kernel(const float* __restrict__ Wp1,
                            const float* __restrict__ Wp2,
                            const float* __restrict__ bp1,
                            const float* __restrict__ bp2,
                            const float* __restrict__ alpha,
                            const float* __restrict__ Wu1,
                            unsigned short* __restrict__ apack,
                            unsigned short* __restrict__ u1pack,
                            float* __restrict__ bfu) {
  int i = blockIdx.x * 256 + threadIdx.x;
  if (i < 5120) {
    int j = i & 7, lane = (i >> 3) & 63, tm = i >> 9;
    int mt = tm & 1;
    int o = (lane & 15) + 16 * mt, g = lane >> 4, vt = (tm >> 1) * 4 + g;
    float w = 0.f;
    if (j < 6 && VT_SRC[vt] != 2) {
      int base = o * 54 + j * 9 + VT_TAP[vt];
      w = (VT_SRC[vt] == 0) ? Wp1[base] : Wp2[base] * alpha[o];
    }
    apack[i] = f2bf(w);
  } else if (i < 6144) {
    int i2 = i - 5120;
    int j = i2 & 7, lane = (i2 >> 3) & 63, mt = i2 >> 9;
    int o = (lane & 15) + 16 * mt, g = lane >> 4;
    u1pack[i2] = f2bf(Wu1[o * 32 + 8 * g + j]);
  } else if (i < 6176) {
    int o = i - 6144;
    bfu[o] = bp1[o] + bp2[o] * alpha[o];
  }
}

// ---------------------------------------- 5-step chained stencil launch
// (R8-proven, unchanged)
constexpr int LSTR5 = 264;
constexpr int T5 = 896;

__global__ __launch_bounds__(T5, 7) void stencil5_kernel(
    const float* __restrict__ x, const float* __restrict__ Kl,
    const float* __restrict__ Wq, const float* __restrict__ bq,
    const float* __restrict__ Wk, const float* __restrict__ gIn,
    float* __restrict__ gOut, float* __restrict__ seB,
    float* __restrict__ wsB, float* __restrict__ sAout, int first, int last) {
  __shared__ float buf[28 * LSTR5];  // 29568 B

  const int band = blockIdx.x, b = blockIdx.y;
  const int gy0 = band * 16 - 5;
  const int t = threadIdx.x;
  const int sx = t & 63, sy = t >> 6;
  const int c0 = 4 * sx, r0 = 2 * sy;
  const float* xim = x + (size_t)b * NPIX;
  const float* gim = (gIn ? gIn : x) + (size_t)b * NPIX;

  if (t < 224) {
    int r = t >> 3, pw = t & 7;
    buf[r * LSTR5 + (pw < 4 ? pw : 256 + pw)] = 0.f;
  }

  const float k00 = Kl[0], k01 = Kl[1], k02 = Kl[2];
  const float k10 = Kl[3], k11 = Kl[4], k12 = Kl[5];
  const float k20 = Kl[6], k21 = Kl[7], k22 = Kl[8];

  const float swk = Wq[0] * Wk[0] + Wq[1] * Wk[1] + Wq[2] * Wk[2];
  const float sbk = bq[0] * Wk[0] + bq[1] * Wk[1] + bq[2] * Wk[2];
  const float rs3 = 0.57735026918962576f;
  const float a1 = swk * rs3, a0c = sbk * rs3;

  const int img_lo = (gy0 < 0) ? -gy0 : 0;
  const int img_hi = (255 - gy0 < 25) ? (255 - gy0) : 25;

  float xv[2][4], g[2][4], se[2][4], ws[2][4];
#pragma unroll
  for (int rr = 0; rr < 2; rr++) {
    int ry = r0 + rr, gy = gy0 + ry;
    bool rin = (ry >= img_lo) && (ry <= img_hi);
    bool tile = (ry >= 5) && (ry <= 20);
    size_t gi = (size_t)b * NPIX + (size_t)gy * WW + c0;
    f32x4 xvv = {0.f, 0.f, 0.f, 0.f}, gvv = {0.f, 0.f, 0.f, 0.f};
    if (rin) {
      xvv = *(const f32x4*)&xim[(size_t)gy * WW + c0];
      gvv = first ? xvv : *(const f32x4*)&gim[(size_t)gy * WW + c0];
    }
    f32x4 sev = {0.f, 0.f, 0.f, 0.f}, wsv = {0.f, 0.f, 0.f, 0.f};
    if (!first && tile) {
      sev = *(const f32x4*)&seB[gi];
      wsv = *(const f32x4*)&wsB[gi];
    }
#pragma unroll
    for (int c = 0; c < 4; c++) {
      xv[rr][c] = xvv[c];
      g[rr][c] = gvv[c];
      se[rr][c] = sev[c];
      ws[rr][c] = wsv[c];
    }
  }

  const int rt = (sy == 0) ? 0 : r0 - 1;
  const int rb = (sy == 13) ? 27 : r0 + 2;

  for (int s = 0; s < 5; s++) {
    if (s) __syncthreads();
    float m[2][4];
#pragma unroll
    for (int rr = 0; rr < 2; rr++) {
      f32x4 mv;
#pragma unroll
      for (int c = 0; c < 4; c++) {
        m[rr][c] = R_C * g[rr][c] * (1.f - g[rr][c]);
        mv[c] = m[rr][c];
      }
      *(f32x4*)&buf[(r0 + rr) * LSTR5 + 4 + c0] = mv;
    }
    __syncthreads();

    f32x4 T4 = *(const f32x4*)&buf[rt * LSTR5 + 4 + c0];
    f32x4 B4 = *(const f32x4*)&buf[rb * LSTR5 + 4 + c0];
    float tl = buf[rt * LSTR5 + 3 + c0], tr = buf[rt * LSTR5 + 8 + c0];
    float bl = buf[rb * LSTR5 + 3 + c0], br = buf[rb * LSTR5 + 8 + c0];
    float sl0 = buf[r0 * LSTR5 + 3 + c0], sr0 = buf[r0 * LSTR5 + 8 + c0];
    float sl1 = buf[(r0 + 1) * LSTR5 + 3 + c0],
          sr1 = buf[(r0 + 1) * LSTR5 + 8 + c0];

    float rT[6], rA[6], rB6[6], rC[6];
    rT[0] = tl; rT[1] = T4[0]; rT[2] = T4[1]; rT[3] = T4[2]; rT[4] = T4[3];
    rT[5] = tr;
    rA[0] = sl0; rB6[0] = sl1;
#pragma unroll
    for (int c = 0; c < 4; c++) { rA[1 + c] = m[0][c]; rB6[1 + c] = m[1][c]; }
    rA[5] = sr0; rB6[5] = sr1;
    rC[0] = bl; rC[1] = B4[0]; rC[2] = B4[1]; rC[3] = B4[2]; rC[4] = B4[3];
    rC[5] = br;

    const int ulo = (s + 1 > img_lo) ? s + 1 : img_lo;
    const int uhi = (24 - s < img_hi) ? 24 - s : img_hi;

    if (r0 >= ulo && r0 <= uhi) {
#pragma unroll
      for (int c = 0; c < 4; c++) {
        float mc = rA[c + 1];
        float loc = k00 * rT[c] + k01 * rT[c + 1] + k02 * rT[c + 2] +
                    k10 * rA[c] + k11 * mc + k12 * rA[c + 2] +
                    k20 * rB6[c] + k21 * rB6[c + 1] + k22 * rB6[c + 2];
        float ph = (1.f - EPS_C) * mc + EPS_C * loc;
        float gn = (1.f - BETA_C) * ph + BETA_C * xv[0][c];
        g[0][c] = fminf(fmaxf(gn, CLAMP_LO), CLAMP_HI);
      }
    }
    if (r0 + 1 >= ulo && r0 + 1 <= uhi) {
#pragma unroll
      for (int c = 0; c < 4; c++) {
        float mc = rB6[c + 1];
        float loc = k00 * rA[c] + k01 * rA[c + 1] + k02 * rA[c + 2] +
                    k10 * rB6[c] + k11 * mc + k12 * rB6[c + 2] +
                    k20 * rC[c] + k21 * rC[c + 1] + k22 * rC[c + 2];
        float ph = (1.f - EPS_C) * mc + EPS_C * loc;
        float gn = (1.f - BETA_C) * ph + BETA_C * xv[1][c];
        g[1][c] = fminf(fmaxf(gn, CLAMP_LO), CLAMP_HI);
      }
    }
#pragma unroll
    for (int rr = 0; rr < 2; rr++) {
      int ry = r0 + rr;
      if (ry >= 5 && ry <= 20) {
#pragma unroll
        for (int c = 0; c < 4; c++) {
          float gv = g[rr][c];
          float e = __expf((a1 * xv[rr][c] + a0c) * gv);
          se[rr][c] += e;
          ws[rr][c] = fmaf(e, gv, ws[rr][c]);
        }
      }
    }
  }

#pragma unroll
  for (int rr = 0; rr < 2; rr++) {
    int ry = r0 + rr;
    if (ry >= 5 && ry <= 20) {
      int gy = gy0 + ry;
      size_t gi = (size_t)b * NPIX + (size_t)gy * WW + c0;
      f32x4 gv;
#pragma unroll
      for (int c = 0; c < 4; c++) gv[c] = g[rr][c];
      *(f32x4*)&gOut[gi] = gv;
      if (last) {
        f32x4 sv;
#pragma unroll
        for (int c = 0; c < 4; c++) sv[c] = ws[rr][c] / se[rr][c];
        *(f32x4*)&sAout[gi] = sv;
      } else {
        f32x4 sev, wsv;
#pragma unroll
        for (int c = 0; c < 4; c++) { sev[c] = se[rr][c]; wsv[c] = ws[rr][c]; }
        *(f32x4*)&seB[gi] = sev;
        *(f32x4*)&wsB[gi] = wsv;
      }
    }
  }
}

// --------------------------- fallback single-launch stencil (R7, proven)
constexpr int BANDH = 16;
constexpr int LSTR2 = 264;
constexpr int TS = 768;

__global__ __launch_bounds__(TS) void stencil_kernel(
    const float* __restrict__ x, const float* __restrict__ Kl,
    const float* __restrict__ Wq, const float* __restrict__ bq,
    const float* __restrict__ Wk, float* __restrict__ lastO,
    float* __restrict__ sO) {
  __shared__ float buf[48 * LSTR2];

  const int band = blockIdx.x, b = blockIdx.y;
  const int gy0 = band * BANDH - 15;
  const int t = threadIdx.x;
  const int sx = t & 63, sy = t >> 6;
  const int c0 = 4 * sx, r0 = 4 * sy;
  const float* xim = x + (size_t)b * NPIX;

  if (t < 384) {
    int r = t >> 3, pw = t & 7;
    buf[r * LSTR2 + (pw < 4 ? pw : 256 + pw)] = 0.f;
  }

  const float k00 = Kl[0], k01 = Kl[1], k02 = Kl[2];
  const float k10 = Kl[3], k11 = Kl[4], k12 = Kl[5];
  const float k20 = Kl[6], k21 = Kl[7], k22 = Kl[8];

  const float swk = Wq[0] * Wk[0] + Wq[1] * Wk[1] + Wq[2] * Wk[2];
  const float sbk = bq[0] * Wk[0] + bq[1] * Wk[1] + bq[2] * Wk[2];
  const float rs3 = 0.57735026918962576f;
  const float a1 = swk * rs3, a0c = sbk * rs3;

  const int img_lo = (gy0 < 0) ? -gy0 : 0;
  const int img_hi = (255 - gy0 < 45) ? (255 - gy0) : 45;

  float xv[4][4], g[4][4], se[4][4], ws[4][4];
#pragma unroll
  for (int rr = 0; rr < 4; rr++) {
    int ry = r0 + rr, gy = gy0 + ry;
    bool rin = (ry >= img_lo) && (ry <= img_hi);
    f32x4 v = {0.f, 0.f, 0.f, 0.f};
    if (rin) v = *(const f32x4*)&xim[gy * WW + c0];
#pragma unroll
    for (int c = 0; c < 4; c++) {
      xv[rr][c] = v[c];
      g[rr][c] = v[c];
      se[rr][c] = 0.f;
      ws[rr][c] = 0.f;
    }
  }

  const int rt = (sy == 0) ? 0 : r0 - 1;
  const int rb = (sy == 11) ? 47 : r0 + 4;

  for (int s = 0; s < STEPS; s++) {
    if (s) __syncthreads();
    float m[4][4];
#pragma unroll
    for (int rr = 0; rr < 4; rr++) {
      f32x4 mv;
#pragma unroll
      for (int c = 0; c < 4; c++) {
        m[rr][c] = R_C * g[rr][c] * (1.f - g[rr][c]);
        mv[c] = m[rr][c];
      }
      *(f32x4*)&buf[(r0 + rr) * LSTR2 + 4 + c0] = mv;
    }
    __syncthreads();

    f32x4 T4 = *(const f32x4*)&buf[rt * LSTR2 + 4 + c0];
    float TL = buf[rt * LSTR2 + 3 + c0];
    float TR = buf[rt * LSTR2 + 8 + c0];
    f32x4 B4 = *(const f32x4*)&buf[rb * LSTR2 + 4 + c0];
    float BL = buf[rb * LSTR2 + 3 + c0];
    float BR = buf[rb * LSTR2 + 8 + c0];
    float sl[4], sr[4];
#pragma unroll
    for (int rr = 0; rr < 4; rr++) {
      sl[rr] = buf[(r0 + rr) * LSTR2 + 3 + c0];
      sr[rr] = buf[(r0 + rr) * LSTR2 + 8 + c0];
    }

    float W[6][6];
    W[0][0] = TL; W[0][1] = T4[0]; W[0][2] = T4[1];
    W[0][3] = T4[2]; W[0][4] = T4[3]; W[0][5] = TR;
#pragma unroll
    for (int rr = 0; rr < 4; rr++) {
      W[1 + rr][0] = sl[rr];
#pragma unroll
      for (int c = 0; c < 4; c++) W[1 + rr][1 + c] = m[rr][c];
      W[1 + rr][5] = sr[rr];
    }
    W[5][0] = BL; W[5][1] = B4[0]; W[5][2] = B4[1];
    W[5][3] = B4[2]; W[5][4] = B4[3]; W[5][5] = BR;

    const int ulo = (s + 1 > img_lo) ? s + 1 : img_lo;
    const int uhi = (44 - s < img_hi) ? 44 - s : img_hi;

#pragma unroll
    for (int rr = 0; rr < 4; rr++) {
      const int ry = r0 + rr;
      if (ry >= ulo && ry <= uhi) {
#pragma unroll
        for (int c = 0; c < 4; c++) {
          float mc = W[rr + 1][c + 1];
          float loc = k00 * W[rr][c] + k01 * W[rr][c + 1] +
                      k02 * W[rr][c + 2] + k10 * W[rr + 1][c] + k11 * mc +
                      k12 * W[rr + 1][c + 2] + k20 * W[rr + 2][c] +
                      k21 * W[rr + 2][c + 1] + k22 * W[rr + 2][c + 2];
          float ph = (1.f - EPS_C) * mc + EPS_C * loc;
          float gn = (1.f - BETA_C) * ph + BETA_C * xv[rr][c];
          g[rr][c] = fminf(fmaxf(gn, CLAMP_LO), CLAMP_HI);
        }
      }
      if (ry >= 15 && ry <= 30) {
#pragma unroll
        for (int c = 0; c < 4; c++) {
          float gv = g[rr][c];
          float e = __expf((a1 * xv[rr][c] + a0c) * gv);
          se[rr][c] += e;
          ws[rr][c] = fmaf(e, gv, ws[rr][c]);
        }
      }
    }
  }

#pragma unroll
  for (int rr = 0; rr < 4; rr++) {
    const int ry = r0 + rr;
    if (ry >= 15 && ry <= 30) {
      int gy = gy0 + ry;
      size_t gi = (size_t)b * NPIX + (size_t)gy * WW + c0;
      f32x4 gv, sv;
#pragma unroll
      for (int c = 0; c < 4; c++) {
        gv[c] = g[rr][c];
        sv[c] = ws[rr][c] / se[rr][c];
      }
      *(f32x4*)&lastO[gi] = gv;
      *(f32x4*)&sO[gi] = sv;
    }
  }
}

// ------------------------------------------------- conv stack via MFMA
// R10: outL removed (direct 64B coalesced per-wave stores) -> LDS 26,944B
// -> 6 blocks/CU (was 5 at 31,232B); launch_bounds(256,6) pins the tier.
constexpr int CT = 32;
constexpr int NR = 36, NCS = 37;
constexpr int FSTR = 44;
constexpr int T2 = 256;

__global__ __launch_bounds__(T2, 6) void conv_kernel(
    const float* __restrict__ x, const float* __restrict__ lastA,
    const float* __restrict__ sA, const float* __restrict__ Wv,
    const float* __restrict__ bv, const unsigned short* __restrict__ apackG,
    const unsigned short* __restrict__ u1packG,
    const float* __restrict__ bfuG, const float* __restrict__ bu1G,
    const float* __restrict__ Wu2G, const float* __restrict__ bu2G,
    float* __restrict__ outp) {
  __shared__ __align__(16) unsigned short ncaL[NR * NCS * 8];   // 21312 B
  __shared__ __align__(16) unsigned short featL[4 * 16 * FSTR]; // 5632 B

  const int cx0 = blockIdx.x * CT, cy0 = blockIdx.y * CT, b = blockIdx.z;
  const int t = threadIdx.x;
  const int w = t >> 6, lane = t & 63;
  const int g = lane >> 4, col = lane & 15;

  const float wv0 = Wv[0], wv1 = Wv[1], wv2 = Wv[2];
  const float bv0 = bv[0], bv1 = bv[1], bv2 = bv[2];
  for (int i = t; i < NR * NR; i += T2) {
    int ry = i / NR, rx = i - ry * NR;
    int gy = cy0 - 2 + ry, gx = cx0 - 2 + rx;
    uint4 val = {0u, 0u, 0u, 0u};
    if (gy >= 0 && gy < HH && gx >= 0 && gx < WW) {
      size_t gi = (size_t)b * NPIX + (size_t)gy * WW + gx;
      float xvv = x[gi], lv = lastA[gi], sv = sA[gi];
      val.x = cvtpk(xvv, lv);
      val.y = cvtpk(lv - xvv, fmaf(wv0, sv, bv0));
      val.z = cvtpk(fmaf(wv1, sv, bv1), fmaf(wv2, sv, bv2));
    }
    *(uint4*)&ncaL[(ry * NCS + rx) * 8] = val;
  }

  const short8* ap = (const short8*)apackG;
  short8 wfr[10];
#pragma unroll
  for (int q = 0; q < 10; q++) wfr[q] = ap[q * 64 + lane];
  const short8* up = (const short8*)u1packG;
  short8 u1fr[2];
  u1fr[0] = up[lane];
  u1fr[1] = up[64 + lane];

  float bf0[4], bf1[4], bu1a[4], bu1b[4], wu2a[4], wu2b[4];
#pragma unroll
  for (int r = 0; r < 4; r++) {
    bf0[r] = bfuG[4 * g + r];
    bf1[r] = bfuG[16 + 4 * g + r];
    bu1a[r] = bu1G[4 * g + r];
    bu1b[r] = bu1G[16 + 4 * g + r];
    wu2a[r] = Wu2G[4 * g + r];
    wu2b[r] = Wu2G[16 + 4 * g + r];
  }
  const float bu2v = bu2G[0];

  int bofft[5];
#pragma unroll
  for (int tt = 0; tt < 5; tt++) {
    int vt = 4 * tt + g;
    bofft[tt] = VT_OY[vt] * NCS + VT_OX[vt];
  }

  __syncthreads();

  unsigned short* fw = &featL[w * 16 * FSTR];

  for (int rr = 0; rr < 8; rr++) {
    int py = 8 * w + rr;
#pragma unroll
    for (int half = 0; half < 2; half++) {
      int px0 = 16 * half;
      int cbase = py * NCS + px0 + col;
      f32x4 a0, a1v;
#pragma unroll
      for (int r = 0; r < 4; r++) { a0[r] = bf0[r]; a1v[r] = bf1[r]; }
#pragma unroll
      for (int tt = 0; tt < 5; tt++) {
        short8 bf = *(const short8*)&ncaL[(cbase + bofft[tt]) * 8];
        a0 = __builtin_amdgcn_mfma_f32_16x16x32_bf16(wfr[2 * tt], bf, a0, 0, 0, 0);
        a1v = __builtin_amdgcn_mfma_f32_16x16x32_bf16(wfr[2 * tt + 1], bf, a1v, 0, 0, 0);
      }
      // relu + pack (cvt_pk) -> per-wave LDS scratch
      uint2 wv_a, wv_b;
      wv_a.x = cvtpk(fmaxf(a0[0], 0.f), fmaxf(a0[1], 0.f));
      wv_a.y = cvtpk(fmaxf(a0[2], 0.f), fmaxf(a0[3], 0.f));
      wv_b.x = cvtpk(fmaxf(a1v[0], 0.f), fmaxf(a1v[1], 0.f));
      wv_b.y = cvtpk(fmaxf(a1v[2], 0.f), fmaxf(a1v[3], 0.f));
      *(uint2*)&fw[col * FSTR + 4 * g] = wv_a;
      *(uint2*)&fw[col * FSTR + 16 + 4 * g] = wv_b;
      short8 pf = *(const short8*)&fw[col * FSTR + 8 * g];
      f32x4 hA, hB;
#pragma unroll
      for (int r = 0; r < 4; r++) { hA[r] = bu1a[r]; hB[r] = bu1b[r]; }
      hA = __builtin_amdgcn_mfma_f32_16x16x32_bf16(u1fr[0], pf, hA, 0, 0, 0);
      hB = __builtin_amdgcn_mfma_f32_16x16x32_bf16(u1fr[1], pf, hB, 0, 0, 0);
      float cp = 0.f;
#pragma unroll
      for (int r = 0; r < 4; r++) {
        cp += wu2a[r] * fmaxf(hA[r], 0.f);
        cp += wu2b[r] * fmaxf(hB[r], 0.f);
      }
      cp += __shfl_xor(cp, 16);
      cp += __shfl_xor(cp, 32);
      float lastv = lastA[(size_t)b * NPIX + (size_t)(cy0 + py) * WW +
                          (cx0 + px0 + col)];
      float ov = fminf(fmaxf(lastv + bu2v + cp, 0.f), 1.f);
      // direct store: 16 lanes x 4B = one 64B coalesced transaction
      if (lane < 16)
        outp[(size_t)b * NPIX + (size_t)(cy0 + py) * WW + (cx0 + px0 + col)] = ov;
    }
  }
}

extern "C" void kernel_launch(void* const* d_in, const int* in_sizes, int n_in,
                              void* d_out, int out_size, void* d_ws,
                              size_t ws_size, hipStream_t stream) {
  const float* x = (const float*)d_in[0];
  const float* Kl = (const float*)d_in[1];
  const float* Wq = (const float*)d_in[2];
  const float* bq = (const float*)d_in[3];
  const float* Wk = (const float*)d_in[4];
  // d_in[5] = bk: softmax-invariant, unused
  const float* Wv = (const float*)d_in[6];
  const float* bv = (const float*)d_in[7];
  const float* Wp1 = (const float*)d_in[8];
  const float* bp1 = (const float*)d_in[9];
  const float* Wp2 = (const float*)d_in[10];
  const float* bp2 = (const float*)d_in[11];
  const float* alpha = (const float*)d_in[12];
  const float* Wu1 = (const float*)d_in[13];
  const float* bu1 = (const float*)d_in[14];
  const float* Wu2 = (const float*)d_in[15];
  const float* bu2 = (const float*)d_in[16];
  float* outp = (float*)d_out;

  const size_t BN = (size_t)BATCH * NPIX;
  float* ws = (float*)d_ws;
  const size_t packF = 5120 / 2 + 1024 / 2 + 64;
  const size_t need3 = (4 * BN + packF) * sizeof(float);

  if (ws_size >= need3) {
    float* gB = ws;
    float* gC = ws + BN;
    float* seB = ws + 2 * BN;
    float* wsB = ws + 3 * BN;
    unsigned short* apack = (unsigned short*)(ws + 4 * BN);
    unsigned short* u1pack = apack + 5120;
    float* bfu = (float*)(u1pack + 1024);

    prep_kernel<<<25, 256, 0, stream>>>(Wp1, Wp2, bp1, bp2, alpha, Wu1, apack,
                                        u1pack, bfu);
    dim3 g1(16, BATCH);
    stencil5_kernel<<<g1, T5, 0, stream>>>(x, Kl, Wq, bq, Wk, nullptr, gB,
                                           seB, wsB, nullptr, 1, 0);
    stencil5_kernel<<<g1, T5, 0, stream>>>(x, Kl, Wq, bq, Wk, gB, gC, seB,
                                           wsB, nullptr, 0, 0);
    stencil5_kernel<<<g1, T5, 0, stream>>>(x, Kl, Wq, bq, Wk, gC, gB, seB,
                                           wsB, seB, 0, 1);
    dim3 g2(WW / CT, HH / CT, BATCH);
    conv_kernel<<<g2, T2, 0, stream>>>(x, gB, seB, Wv, bv, apack, u1pack,
                                       bfu, bu1, Wu2, bu2, outp);
  } else {
    float* lastW = ws;
    float* sW = ws + BN;
    unsigned short* apack = (unsigned short*)(ws + 2 * BN);
    unsigned short* u1pack = apack + 5120;
    float* bfu = (float*)(u1pack + 1024);

    prep_kernel<<<25, 256, 0, stream>>>(Wp1, Wp2, bp1, bp2, alpha, Wu1, apack,
                                        u1pack, bfu);
    dim3 g1(HH / BANDH, BATCH);
    stencil_kernel<<<g1, TS, 0, stream>>>(x, Kl, Wq, bq, Wk, lastW, sW);
    dim3 g2(WW / CT, HH / CT, BATCH);
    conv_kernel<<<g2, T2, 0, stream>>>(x, lastW, sW, Wv, bv, apack, u1pack,
                                       bfu, bu1, Wu2, bu2, outp);
  }
}

// Round 12
// 128.595 us; speedup vs baseline: 1.9145x; 1.9145x over previous
//
#include <hip/hip_runtime.h>

constexpr int BATCH = 32;
constexpr int HH = 256, WW = 256;
constexpr int NPIX = HH * WW;
constexpr int STEPS = 15;
constexpr float R_C = 3.9f, EPS_C = 0.3f, BETA_C = 0.15f;
constexpr float CLAMP_LO = 1e-4f, CLAMP_HI = 1.0f - 1e-4f;

typedef __attribute__((ext_vector_type(8))) short short8;
typedef __attribute__((ext_vector_type(4))) float f32x4;

__device__ inline unsigned short f2bf(float f) {
  unsigned int u = __float_as_uint(f);
  return (unsigned short)((u + 0x7fffu + ((u >> 16) & 1u)) >> 16);
}

// packed f32x2 -> bf16x2 (RNE, bit-identical to f2bf pair); gfx950 VALU op
__device__ inline unsigned cvtpk(float lo, float hi) {
  unsigned r;
  asm("v_cvt_pk_bf16_f32 %0, %1, %2" : "=v"(r) : "v"(lo), "v"(hi));
  return r;
}

__constant__ int VT_OY[20] = {1,2,3,1, 3,0,0,2, 0,2,2,4, 4,4,3,2, 0,0,2,1};
__constant__ int VT_OX[20] = {3,2,3,1, 1,4,2,4, 0,2,0,2, 4,0,2,1, 1,3,3,2};
__constant__ int VT_SRC[20]= {0,0,0,0, 0,1,1,1, 1,1,1,1, 1,1,0,0, 2,2,0,0};
__constant__ int VT_TAP[20]= {2,4,8,0, 6,2,1,5, 0,4,3,7, 8,6,7,3, 0,0,5,1};

// ------------------------------------------------------------------ prep
__global__ void prep_kernel(const float* __restrict__ Wp1,
                            const float* __restrict__ Wp2,
                            const float* __restrict__ bp1,
                            const float* __restrict__ bp2,
                            const float* __restrict__ alpha,
                            const float* __restrict__ Wu1,
                            unsigned short* __restrict__ apack,
                            unsigned short* __restrict__ u1pack,
                            float* __restrict__ bfu) {
  int i = blockIdx.x * 256 + threadIdx.x;
  if (i < 5120) {
    int j = i & 7, lane = (i >> 3) & 63, tm = i >> 9;
    int mt = tm & 1;
    int o = (lane & 15) + 16 * mt, g = lane >> 4, vt = (tm >> 1) * 4 + g;
    float w = 0.f;
    if (j < 6 && VT_SRC[vt] != 2) {
      int base = o * 54 + j * 9 + VT_TAP[vt];
      w = (VT_SRC[vt] == 0) ? Wp1[base] : Wp2[base] * alpha[o];
    }
    apack[i] = f2bf(w);
  } else if (i < 6144) {
    int i2 = i - 5120;
    int j = i2 & 7, lane = (i2 >> 3) & 63, mt = i2 >> 9;
    int o = (lane & 15) + 16 * mt, g = lane >> 4;
    u1pack[i2] = f2bf(Wu1[o * 32 + 8 * g + j]);
  } else if (i < 6176) {
    int o = i - 6144;
    bfu[o] = bp1[o] + bp2[o] * alpha[o];
  }
}

// ---------------------------------------- 5-step chained stencil launch
// R12: LDS `mapped` buffer DOUBLE-buffered (2 x 28 x 264 words = 59 KB),
// ONE barrier per step (R4-proven race-free-by-construction: step-s reads
// of buf[p] are separated from the next write to buf[p] (step s+2) by two
// barrier crossings, and the compiler drains lgkmcnt before each
// s_barrier).  Occupancy unchanged: 14-wave blocks are wave-limited to
// 2 blocks/CU either way.  Replaces the single-buffer write/bar/read/bar
// loop — the only structure whose safety was codegen-dependent (R11
// post-timing divergence suspect).
constexpr int LSTR5 = 264;
constexpr int T5 = 896;

__global__ __launch_bounds__(T5, 7) void stencil5_kernel(
    const float* __restrict__ x, const float* __restrict__ Kl,
    const float* __restrict__ Wq, const float* __restrict__ bq,
    const float* __restrict__ Wk, const float* __restrict__ gIn,
    float* __restrict__ gOut, float* __restrict__ seB,
    float* __restrict__ wsB, float* __restrict__ sAout, int first, int last) {
  __shared__ float hbuf[2][28 * LSTR5];  // 59136 B

  const int band = blockIdx.x, b = blockIdx.y;
  const int gy0 = band * 16 - 5;
  const int t = threadIdx.x;
  const int sx = t & 63, sy = t >> 6;
  const int c0 = 4 * sx, r0 = 2 * sy;
  const float* xim = x + (size_t)b * NPIX;
  const float* gim = (gIn ? gIn : x) + (size_t)b * NPIX;

  // zero pad columns of BOTH buffers (2 x 28 rows x 8 words); fenced by
  // the first barrier before any read
  if (t < 448) {
    int bi = t >= 224;
    int tt = t - bi * 224;
    int r = tt >> 3, pw = tt & 7;
    hbuf[bi][r * LSTR5 + (pw < 4 ? pw : 256 + pw)] = 0.f;
  }

  const float k00 = Kl[0], k01 = Kl[1], k02 = Kl[2];
  const float k10 = Kl[3], k11 = Kl[4], k12 = Kl[5];
  const float k20 = Kl[6], k21 = Kl[7], k22 = Kl[8];

  const float swk = Wq[0] * Wk[0] + Wq[1] * Wk[1] + Wq[2] * Wk[2];
  const float sbk = bq[0] * Wk[0] + bq[1] * Wk[1] + bq[2] * Wk[2];
  const float rs3 = 0.57735026918962576f;
  const float a1 = swk * rs3, a0c = sbk * rs3;

  const int img_lo = (gy0 < 0) ? -gy0 : 0;
  const int img_hi = (255 - gy0 < 25) ? (255 - gy0) : 25;

  float xv[2][4], g[2][4], se[2][4], ws[2][4];
#pragma unroll
  for (int rr = 0; rr < 2; rr++) {
    int ry = r0 + rr, gy = gy0 + ry;
    bool rin = (ry >= img_lo) && (ry <= img_hi);
    bool tile = (ry >= 5) && (ry <= 20);
    size_t gi = (size_t)b * NPIX + (size_t)gy * WW + c0;
    f32x4 xvv = {0.f, 0.f, 0.f, 0.f}, gvv = {0.f, 0.f, 0.f, 0.f};
    if (rin) {
      xvv = *(const f32x4*)&xim[(size_t)gy * WW + c0];
      gvv = first ? xvv : *(const f32x4*)&gim[(size_t)gy * WW + c0];
    }
    f32x4 sev = {0.f, 0.f, 0.f, 0.f}, wsv = {0.f, 0.f, 0.f, 0.f};
    if (!first && tile) {
      sev = *(const f32x4*)&seB[gi];
      wsv = *(const f32x4*)&wsB[gi];
    }
#pragma unroll
    for (int c = 0; c < 4; c++) {
      xv[rr][c] = xvv[c];
      g[rr][c] = gvv[c];
      se[rr][c] = sev[c];
      ws[rr][c] = wsv[c];
    }
  }

  const int rt = (sy == 0) ? 0 : r0 - 1;
  const int rb = (sy == 13) ? 27 : r0 + 2;

  for (int s = 0; s < 5; s++) {
    float* buf = hbuf[s & 1];
    float m[2][4];
#pragma unroll
    for (int rr = 0; rr < 2; rr++) {
      f32x4 mv;
#pragma unroll
      for (int c = 0; c < 4; c++) {
        m[rr][c] = R_C * g[rr][c] * (1.f - g[rr][c]);
        mv[c] = m[rr][c];
      }
      *(f32x4*)&buf[(r0 + rr) * LSTR5 + 4 + c0] = mv;
    }
    __syncthreads();

    f32x4 T4 = *(const f32x4*)&buf[rt * LSTR5 + 4 + c0];
    f32x4 B4 = *(const f32x4*)&buf[rb * LSTR5 + 4 + c0];
    float tl = buf[rt * LSTR5 + 3 + c0], tr = buf[rt * LSTR5 + 8 + c0];
    float bl = buf[rb * LSTR5 + 3 + c0], br = buf[rb * LSTR5 + 8 + c0];
    float sl0 = buf[r0 * LSTR5 + 3 + c0], sr0 = buf[r0 * LSTR5 + 8 + c0];
    float sl1 = buf[(r0 + 1) * LSTR5 + 3 + c0],
          sr1 = buf[(r0 + 1) * LSTR5 + 8 + c0];

    float rT[6], rA[6], rB6[6], rC[6];
    rT[0] = tl; rT[1] = T4[0]; rT[2] = T4[1]; rT[3] = T4[2]; rT[4] = T4[3];
    rT[5] = tr;
    rA[0] = sl0; rB6[0] = sl1;
#pragma unroll
    for (int c = 0; c < 4; c++) { rA[1 + c] = m[0][c]; rB6[1 + c] = m[1][c]; }
    rA[5] = sr0; rB6[5] = sr1;
    rC[0] = bl; rC[1] = B4[0]; rC[2] = B4[1]; rC[3] = B4[2]; rC[4] = B4[3];
    rC[5] = br;

    const int ulo = (s + 1 > img_lo) ? s + 1 : img_lo;
    const int uhi = (24 - s < img_hi) ? 24 - s : img_hi;

    if (r0 >= ulo && r0 <= uhi) {
#pragma unroll
      for (int c = 0; c < 4; c++) {
        float mc = rA[c + 1];
        float loc = k00 * rT[c] + k01 * rT[c + 1] + k02 * rT[c + 2] +
                    k10 * rA[c] + k11 * mc + k12 * rA[c + 2] +
                    k20 * rB6[c] + k21 * rB6[c + 1] + k22 * rB6[c + 2];
        float ph = (1.f - EPS_C) * mc + EPS_C * loc;
        float gn = (1.f - BETA_C) * ph + BETA_C * xv[0][c];
        g[0][c] = fminf(fmaxf(gn, CLAMP_LO), CLAMP_HI);
      }
    }
    if (r0 + 1 >= ulo && r0 + 1 <= uhi) {
#pragma unroll
      for (int c = 0; c < 4; c++) {
        float mc = rB6[c + 1];
        float loc = k00 * rA[c] + k01 * rA[c + 1] + k02 * rA[c + 2] +
                    k10 * rB6[c] + k11 * mc + k12 * rB6[c + 2] +
                    k20 * rC[c] + k21 * rC[c + 1] + k22 * rC[c + 2];
        float ph = (1.f - EPS_C) * mc + EPS_C * loc;
        float gn = (1.f - BETA_C) * ph + BETA_C * xv[1][c];
        g[1][c] = fminf(fmaxf(gn, CLAMP_LO), CLAMP_HI);
      }
    }
#pragma unroll
    for (int rr = 0; rr < 2; rr++) {
      int ry = r0 + rr;
      if (ry >= 5 && ry <= 20) {
#pragma unroll
        for (int c = 0; c < 4; c++) {
          float gv = g[rr][c];
          float e = __expf((a1 * xv[rr][c] + a0c) * gv);
          se[rr][c] += e;
          ws[rr][c] = fmaf(e, gv, ws[rr][c]);
        }
      }
    }
  }

#pragma unroll
  for (int rr = 0; rr < 2; rr++) {
    int ry = r0 + rr;
    if (ry >= 5 && ry <= 20) {
      int gy = gy0 + ry;
      size_t gi = (size_t)b * NPIX + (size_t)gy * WW + c0;
      f32x4 gv;
#pragma unroll
      for (int c = 0; c < 4; c++) gv[c] = g[rr][c];
      *(f32x4*)&gOut[gi] = gv;
      if (last) {
        f32x4 sv;
#pragma unroll
        for (int c = 0; c < 4; c++) sv[c] = ws[rr][c] / se[rr][c];
        *(f32x4*)&sAout[gi] = sv;
      } else {
        f32x4 sev, wsv;
#pragma unroll
        for (int c = 0; c < 4; c++) { sev[c] = se[rr][c]; wsv[c] = ws[rr][c]; }
        *(f32x4*)&seB[gi] = sev;
        *(f32x4*)&wsB[gi] = wsv;
      }
    }
  }
}

// --------------------------- fallback single-launch stencil (R7, proven)
constexpr int BANDH = 16;
constexpr int LSTR2 = 264;
constexpr int TS = 768;

__global__ __launch_bounds__(TS) void stencil_kernel(
    const float* __restrict__ x, const float* __restrict__ Kl,
    const float* __restrict__ Wq, const float* __restrict__ bq,
    const float* __restrict__ Wk, float* __restrict__ lastO,
    float* __restrict__ sO) {
  __shared__ float buf[48 * LSTR2];

  const int band = blockIdx.x, b = blockIdx.y;
  const int gy0 = band * BANDH - 15;
  const int t = threadIdx.x;
  const int sx = t & 63, sy = t >> 6;
  const int c0 = 4 * sx, r0 = 4 * sy;
  const float* xim = x + (size_t)b * NPIX;

  if (t < 384) {
    int r = t >> 3, pw = t & 7;
    buf[r * LSTR2 + (pw < 4 ? pw : 256 + pw)] = 0.f;
  }

  const float k00 = Kl[0], k01 = Kl[1], k02 = Kl[2];
  const float k10 = Kl[3], k11 = Kl[4], k12 = Kl[5];
  const float k20 = Kl[6], k21 = Kl[7], k22 = Kl[8];

  const float swk = Wq[0] * Wk[0] + Wq[1] * Wk[1] + Wq[2] * Wk[2];
  const float sbk = bq[0] * Wk[0] + bq[1] * Wk[1] + bq[2] * Wk[2];
  const float rs3 = 0.57735026918962576f;
  const float a1 = swk * rs3, a0c = sbk * rs3;

  const int img_lo = (gy0 < 0) ? -gy0 : 0;
  const int img_hi = (255 - gy0 < 45) ? (255 - gy0) : 45;

  float xv[4][4], g[4][4], se[4][4], ws[4][4];
#pragma unroll
  for (int rr = 0; rr < 4; rr++) {
    int ry = r0 + rr, gy = gy0 + ry;
    bool rin = (ry >= img_lo) && (ry <= img_hi);
    f32x4 v = {0.f, 0.f, 0.f, 0.f};
    if (rin) v = *(const f32x4*)&xim[gy * WW + c0];
#pragma unroll
    for (int c = 0; c < 4; c++) {
      xv[rr][c] = v[c];
      g[rr][c] = v[c];
      se[rr][c] = 0.f;
      ws[rr][c] = 0.f;
    }
  }

  const int rt = (sy == 0) ? 0 : r0 - 1;
  const int rb = (sy == 11) ? 47 : r0 + 4;

  for (int s = 0; s < STEPS; s++) {
    if (s) __syncthreads();
    float m[4][4];
#pragma unroll
    for (int rr = 0; rr < 4; rr++) {
      f32x4 mv;
#pragma unroll
      for (int c = 0; c < 4; c++) {
        m[rr][c] = R_C * g[rr][c] * (1.f - g[rr][c]);
        mv[c] = m[rr][c];
      }
      *(f32x4*)&buf[(r0 + rr) * LSTR2 + 4 + c0] = mv;
    }
    __syncthreads();

    f32x4 T4 = *(const f32x4*)&buf[rt * LSTR2 + 4 + c0];
    float TL = buf[rt * LSTR2 + 3 + c0];
    float TR = buf[rt * LSTR2 + 8 + c0];
    f32x4 B4 = *(const f32x4*)&buf[rb * LSTR2 + 4 + c0];
    float BL = buf[rb * LSTR2 + 3 + c0];
    float BR = buf[rb * LSTR2 + 8 + c0];
    float sl[4], sr[4];
#pragma unroll
    for (int rr = 0; rr < 4; rr++) {
      sl[rr] = buf[(r0 + rr) * LSTR2 + 3 + c0];
      sr[rr] = buf[(r0 + rr) * LSTR2 + 8 + c0];
    }

    float W[6][6];
    W[0][0] = TL; W[0][1] = T4[0]; W[0][2] = T4[1];
    W[0][3] = T4[2]; W[0][4] = T4[3]; W[0][5] = TR;
#pragma unroll
    for (int rr = 0; rr < 4; rr++) {
      W[1 + rr][0] = sl[rr];
#pragma unroll
      for (int c = 0; c < 4; c++) W[1 + rr][1 + c] = m[rr][c];
      W[1 + rr][5] = sr[rr];
    }
    W[5][0] = BL; W[5][1] = B4[0]; W[5][2] = B4[1];
    W[5][3] = B4[2]; W[5][4] = B4[3]; W[5][5] = BR;

    const int ulo = (s + 1 > img_lo) ? s + 1 : img_lo;
    const int uhi = (44 - s < img_hi) ? 44 - s : img_hi;

#pragma unroll
    for (int rr = 0; rr < 4; rr++) {
      const int ry = r0 + rr;
      if (ry >= ulo && ry <= uhi) {
#pragma unroll
        for (int c = 0; c < 4; c++) {
          float mc = W[rr + 1][c + 1];
          float loc = k00 * W[rr][c] + k01 * W[rr][c + 1] +
                      k02 * W[rr][c + 2] + k10 * W[rr + 1][c] + k11 * mc +
                      k12 * W[rr + 1][c + 2] + k20 * W[rr + 2][c] +
                      k21 * W[rr + 2][c + 1] + k22 * W[rr + 2][c + 2];
          float ph = (1.f - EPS_C) * mc + EPS_C * loc;
          float gn = (1.f - BETA_C) * ph + BETA_C * xv[rr][c];
          g[rr][c] = fminf(fmaxf(gn, CLAMP_LO), CLAMP_HI);
        }
      }
      if (ry >= 15 && ry <= 30) {
#pragma unroll
        for (int c = 0; c < 4; c++) {
          float gv = g[rr][c];
          float e = __expf((a1 * xv[rr][c] + a0c) * gv);
          se[rr][c] += e;
          ws[rr][c] = fmaf(e, gv, ws[rr][c]);
        }
      }
    }
  }

#pragma unroll
  for (int rr = 0; rr < 4; rr++) {
    const int ry = r0 + rr;
    if (ry >= 15 && ry <= 30) {
      int gy = gy0 + ry;
      size_t gi = (size_t)b * NPIX + (size_t)gy * WW + c0;
      f32x4 gv, sv;
#pragma unroll
      for (int c = 0; c < 4; c++) {
        gv[c] = g[rr][c];
        sv[c] = ws[rr][c] / se[rr][c];
      }
      *(f32x4*)&lastO[gi] = gv;
      *(f32x4*)&sO[gi] = sv;
    }
  }
}

// ------------------------------------------------- conv stack via MFMA
// (R11: no outL, direct coalesced stores, LDS 26,944B -> 6 blocks/CU;
// natural register allocation — NO min-occupancy bound, see R7/R10 spill)
constexpr int CT = 32;
constexpr int NR = 36, NCS = 37;
constexpr int FSTR = 44;
constexpr int T2 = 256;

__global__ __launch_bounds__(T2) void conv_kernel(
    const float* __restrict__ x, const float* __restrict__ lastA,
    const float* __restrict__ sA, const float* __restrict__ Wv,
    const float* __restrict__ bv, const unsigned short* __restrict__ apackG,
    const unsigned short* __restrict__ u1packG,
    const float* __restrict__ bfuG, const float* __restrict__ bu1G,
    const float* __restrict__ Wu2G, const float* __restrict__ bu2G,
    float* __restrict__ outp) {
  __shared__ __align__(16) unsigned short ncaL[NR * NCS * 8];   // 21312 B
  __shared__ __align__(16) unsigned short featL[4 * 16 * FSTR]; // 5632 B

  const int cx0 = blockIdx.x * CT, cy0 = blockIdx.y * CT, b = blockIdx.z;
  const int t = threadIdx.x;
  const int w = t >> 6, lane = t & 63;
  const int g = lane >> 4, col = lane & 15;

  const float wv0 = Wv[0], wv1 = Wv[1], wv2 = Wv[2];
  const float bv0 = bv[0], bv1 = bv[1], bv2 = bv[2];
  for (int i = t; i < NR * NR; i += T2) {
    int ry = i / NR, rx = i - ry * NR;
    int gy = cy0 - 2 + ry, gx = cx0 - 2 + rx;
    uint4 val = {0u, 0u, 0u, 0u};
    if (gy >= 0 && gy < HH && gx >= 0 && gx < WW) {
      size_t gi = (size_t)b * NPIX + (size_t)gy * WW + gx;
      float xvv = x[gi], lv = lastA[gi], sv = sA[gi];
      val.x = cvtpk(xvv, lv);
      val.y = cvtpk(lv - xvv, fmaf(wv0, sv, bv0));
      val.z = cvtpk(fmaf(wv1, sv, bv1), fmaf(wv2, sv, bv2));
    }
    *(uint4*)&ncaL[(ry * NCS + rx) * 8] = val;
  }

  const short8* ap = (const short8*)apackG;
  short8 wfr[10];
#pragma unroll
  for (int q = 0; q < 10; q++) wfr[q] = ap[q * 64 + lane];
  const short8* up = (const short8*)u1packG;
  short8 u1fr[2];
  u1fr[0] = up[lane];
  u1fr[1] = up[64 + lane];

  float bf0[4], bf1[4], bu1a[4], bu1b[4], wu2a[4], wu2b[4];
#pragma unroll
  for (int r = 0; r < 4; r++) {
    bf0[r] = bfuG[4 * g + r];
    bf1[r] = bfuG[16 + 4 * g + r];
    bu1a[r] = bu1G[4 * g + r];
    bu1b[r] = bu1G[16 + 4 * g + r];
    wu2a[r] = Wu2G[4 * g + r];
    wu2b[r] = Wu2G[16 + 4 * g + r];
  }
  const float bu2v = bu2G[0];

  int bofft[5];
#pragma unroll
  for (int tt = 0; tt < 5; tt++) {
    int vt = 4 * tt + g;
    bofft[tt] = VT_OY[vt] * NCS + VT_OX[vt];
  }

  __syncthreads();

  unsigned short* fw = &featL[w * 16 * FSTR];

  for (int rr = 0; rr < 8; rr++) {
    int py = 8 * w + rr;
#pragma unroll
    for (int half = 0; half < 2; half++) {
      int px0 = 16 * half;
      int cbase = py * NCS + px0 + col;
      f32x4 a0, a1v;
#pragma unroll
      for (int r = 0; r < 4; r++) { a0[r] = bf0[r]; a1v[r] = bf1[r]; }
#pragma unroll
      for (int tt = 0; tt < 5; tt++) {
        short8 bf = *(const short8*)&ncaL[(cbase + bofft[tt]) * 8];
        a0 = __builtin_amdgcn_mfma_f32_16x16x32_bf16(wfr[2 * tt], bf, a0, 0, 0, 0);
        a1v = __builtin_amdgcn_mfma_f32_16x16x32_bf16(wfr[2 * tt + 1], bf, a1v, 0, 0, 0);
      }
      // relu + pack (cvt_pk) -> per-wave LDS scratch
      uint2 wv_a, wv_b;
      wv_a.x = cvtpk(fmaxf(a0[0], 0.f), fmaxf(a0[1], 0.f));
      wv_a.y = cvtpk(fmaxf(a0[2], 0.f), fmaxf(a0[3], 0.f));
      wv_b.x = cvtpk(fmaxf(a1v[0], 0.f), fmaxf(a1v[1], 0.f));
      wv_b.y = cvtpk(fmaxf(a1v[2], 0.f), fmaxf(a1v[3], 0.f));
      *(uint2*)&fw[col * FSTR + 4 * g] = wv_a;
      *(uint2*)&fw[col * FSTR + 16 + 4 * g] = wv_b;
      short8 pf = *(const short8*)&fw[col * FSTR + 8 * g];
      f32x4 hA, hB;
#pragma unroll
      for (int r = 0; r < 4; r++) { hA[r] = bu1a[r]; hB[r] = bu1b[r]; }
      hA = __builtin_amdgcn_mfma_f32_16x16x32_bf16(u1fr[0], pf, hA, 0, 0, 0);
      hB = __builtin_amdgcn_mfma_f32_16x16x32_bf16(u1fr[1], pf, hB, 0, 0, 0);
      float cp = 0.f;
#pragma unroll
      for (int r = 0; r < 4; r++) {
        cp += wu2a[r] * fmaxf(hA[r], 0.f);
        cp += wu2b[r] * fmaxf(hB[r], 0.f);
      }
      cp += __shfl_xor(cp, 16);
      cp += __shfl_xor(cp, 32);
      float lastv = lastA[(size_t)b * NPIX + (size_t)(cy0 + py) * WW +
                          (cx0 + px0 + col)];
      float ov = fminf(fmaxf(lastv + bu2v + cp, 0.f), 1.f);
      if (lane < 16)
        outp[(size_t)b * NPIX + (size_t)(cy0 + py) * WW + (cx0 + px0 + col)] = ov;
    }
  }
}

extern "C" void kernel_launch(void* const* d_in, const int* in_sizes, int n_in,
                              void* d_out, int out_size, void* d_ws,
                              size_t ws_size, hipStream_t stream) {
  const float* x = (const float*)d_in[0];
  const float* Kl = (const float*)d_in[1];
  const float* Wq = (const float*)d_in[2];
  const float* bq = (const float*)d_in[3];
  const float* Wk = (const float*)d_in[4];
  // d_in[5] = bk: softmax-invariant, unused
  const float* Wv = (const float*)d_in[6];
  const float* bv = (const float*)d_in[7];
  const float* Wp1 = (const float*)d_in[8];
  const float* bp1 = (const float*)d_in[9];
  const float* Wp2 = (const float*)d_in[10];
  const float* bp2 = (const float*)d_in[11];
  const float* alpha = (const float*)d_in[12];
  const float* Wu1 = (const float*)d_in[13];
  const float* bu1 = (const float*)d_in[14];
  const float* Wu2 = (const float*)d_in[15];
  const float* bu2 = (const float*)d_in[16];
  float* outp = (float*)d_out;

  const size_t BN = (size_t)BATCH * NPIX;
  float* ws = (float*)d_ws;
  const size_t packF = 5120 / 2 + 1024 / 2 + 64;
  const size_t need3 = (4 * BN + packF) * sizeof(float);

  if (ws_size >= need3) {
    float* gB = ws;
    float* gC = ws + BN;
    float* seB = ws + 2 * BN;
    float* wsB = ws + 3 * BN;
    unsigned short* apack = (unsigned short*)(ws + 4 * BN);
    unsigned short* u1pack = apack + 5120;
    float* bfu = (float*)(u1pack + 1024);

    prep_kernel<<<25, 256, 0, stream>>>(Wp1, Wp2, bp1, bp2, alpha, Wu1, apack,
                                        u1pack, bfu);
    dim3 g1(16, BATCH);
    stencil5_kernel<<<g1, T5, 0, stream>>>(x, Kl, Wq, bq, Wk, nullptr, gB,
                                           seB, wsB, nullptr, 1, 0);
    stencil5_kernel<<<g1, T5, 0, stream>>>(x, Kl, Wq, bq, Wk, gB, gC, seB,
                                           wsB, nullptr, 0, 0);
    stencil5_kernel<<<g1, T5, 0, stream>>>(x, Kl, Wq, bq, Wk, gC, gB, seB,
                                           wsB, seB, 0, 1);
    dim3 g2(WW / CT, HH / CT, BATCH);
    conv_kernel<<<g2, T2, 0, stream>>>(x, gB, seB, Wv, bv, apack, u1pack,
                                       bfu, bu1, Wu2, bu2, outp);
  } else {
    float* lastW = ws;
    float* sW = ws + BN;
    unsigned short* apack = (unsigned short*)(ws + 2 * BN);
    unsigned short* u1pack = apack + 5120;
    float* bfu = (float*)(u1pack + 1024);

    prep_kernel<<<25, 256, 0, stream>>>(Wp1, Wp2, bp1, bp2, alpha, Wu1, apack,
                                        u1pack, bfu);
    dim3 g1(HH / BANDH, BATCH);
    stencil_kernel<<<g1, TS, 0, stream>>>(x, Kl, Wq, bq, Wk, lastW, sW);
    dim3 g2(WW / CT, HH / CT, BATCH);
    conv_kernel<<<g2, T2, 0, stream>>>(x, lastW, sW, Wv, bv, apack, u1pack,
                                       bfu, bu1, Wu2, bu2, outp);
  }
}